// Round 7
// baseline (331.691 us; speedup 1.0000x reference)
//
#include <hip/hip_runtime.h>
#include <stdint.h>
#include <type_traits>

// Problem constants
#define BB  4
#define SS  2048
#define DD  1024
#define HH  16
#define HDD 64

typedef __attribute__((ext_vector_type(8))) short s16x8;   // 8 bf16 (4 VGPRs)
typedef __attribute__((ext_vector_type(4))) float f32x4;   // MFMA C/D

__device__ inline short f2bf(float f) {
    union { float f; unsigned int u; } v; v.f = f;
    unsigned int r = (v.u + 0x7fffu + ((v.u >> 16) & 1u)) >> 16; // RNE
    return (short)r;
}

__device__ inline float bf2f(short s) {
    union { unsigned int u; float f; } v;
    v.u = ((unsigned int)(unsigned short)s) << 16;
    return v.f;
}

#define GLL(gp, lp) __builtin_amdgcn_global_load_lds( \
    (const __attribute__((address_space(1))) void*)(gp), \
    (__attribute__((address_space(3))) void*)(lp), 16, 0, 0)

// Raw barrier: orders this wave's LDS ops (lgkmcnt) then syncs. Does NOT
// drain vmcnt -> global_load_lds prefetch stays in flight across it.
__device__ inline void lds_barrier() {
    asm volatile("s_waitcnt lgkmcnt(0)" ::: "memory");
    __builtin_amdgcn_sched_barrier(0);
    __builtin_amdgcn_s_barrier();
    __builtin_amdgcn_sched_barrier(0);
}

// ---------------- fp32 -> bf16 cast (n % 8 == 0) ----------------
__global__ void cvt_kernel(const float* __restrict__ src, short* __restrict__ dst, int n) {
    int i = (blockIdx.x * 256 + threadIdx.x) * 8;
    if (i >= n) return;
    const float4* s = (const float4*)(src + i);
    float4 a = s[0], b = s[1];
    s16x8 o;
    o[0]=f2bf(a.x); o[1]=f2bf(a.y); o[2]=f2bf(a.z); o[3]=f2bf(a.w);
    o[4]=f2bf(b.x); o[5]=f2bf(b.y); o[6]=f2bf(b.z); o[7]=f2bf(b.w);
    *(s16x8*)(dst + i) = o;
}

// ---------------- GEMM C = A @ B^T + bias (BM=128 BN=256 BK=64, GLL dbuf) ----------
// Ported from the attn kernel's PROVEN staging pattern (round 5/6: 0 bank conflicts):
// per K-tile: barrier A (frees buf^1) -> issue 6 GLL for tile t+1 -> vmcnt(6)
// (tile t's 6 drained, t+1's stay IN FLIGHT across barrier B) -> barrier B ->
// 16 swizzled ds_read_b128 + 32 MFMA in a setprio cluster. No vmcnt(0) in-loop.
// Swizzle (rule #21, both-sides): GLL linear dest + inverse-swizzled global source
// (granule ^ row&7) + same XOR on ds_read -> each 8-lane octet covers all 8 slots.
// 512 threads = 8 waves (2M x 4N), per-wave 64x64 output (acc[4][4]).
// LDS 96 KB -> 1 block/CU; grids sized for exact CU rounds (768 = 3x256, 256 = 1x256).
// T1 XCD swizzle on block id (grid % 8 == 0).
template<int EPI>
__global__ __launch_bounds__(512, 2)
void gemm256(const short* __restrict__ A, const short* __restrict__ Bw,
             const float* __restrict__ bias, float* __restrict__ Cf,
             short* __restrict__ Qo, short* __restrict__ Ko, short* __restrict__ Vo,
             int M, int N, int K, int nbx)
{
    __shared__ short lsA[2][128 * 64];
    __shared__ short lsB[2][256 * 64];

    const int tid  = threadIdx.x;
    const int w    = tid >> 6, lane = tid & 63;
    const int quad = lane >> 4, l15 = lane & 15;
    const int wm = w >> 2, wn = w & 3;
    // T1 XCD-aware swizzle (gridDim.x % 8 == 0 guaranteed by launch)
    const int cpx = gridDim.x >> 3;
    const int swz = (blockIdx.x & 7) * cpx + (blockIdx.x >> 3);
    const int m0 = (swz / nbx) * 128, n0 = (swz % nbx) * 256;
    const int grow = lane >> 3;                 // row-within-octet this lane covers
    const int gcol = ((lane & 7) ^ grow) * 8;   // inverse-swizzled source col (shorts)
    const int l7 = l15 & 7;

    f32x4 acc[4][4] = {};

    auto issue = [&](int kt, int buf) {
#pragma unroll
        for (int jj = 0; jj < 2; ++jj) {        // A: 128 rows = 16 octets, 2/wave
            int row = w * 16 + jj * 8 + grow;
            GLL(A + (size_t)(m0 + row) * K + kt * 64 + gcol,
                &lsA[buf][(w * 2 + jj) * 512]);
        }
#pragma unroll
        for (int jj = 0; jj < 4; ++jj) {        // B: 256 rows = 32 octets, 4/wave
            int row = w * 32 + jj * 8 + grow;
            GLL(Bw + (size_t)(n0 + row) * K + kt * 64 + gcol,
                &lsB[buf][(w * 4 + jj) * 512]);
        }
    };

    const int NT = K >> 6;                      // BK=64 K-tiles
    issue(0, 0);
    for (int t = 0; t < NT; ++t) {
        const int buf = t & 1;
        lds_barrier();                          // A: all waves done reading buf^1
        if (t + 1 < NT) {
            issue(t + 1, buf ^ 1);
            asm volatile("s_waitcnt vmcnt(6)" ::: "memory");
        } else {
            asm volatile("s_waitcnt vmcnt(0)" ::: "memory");
        }
        __builtin_amdgcn_sched_barrier(0);
        __builtin_amdgcn_s_barrier();           // B: tile t fully staged (all waves)
        __builtin_amdgcn_sched_barrier(0);

        s16x8 af[4][2], bfr[4][2];
#pragma unroll
        for (int mf = 0; mf < 4; ++mf)
#pragma unroll
            for (int ks = 0; ks < 2; ++ks)
                af[mf][ks] = *(const s16x8*)&lsA[buf][(wm * 64 + mf * 16 + l15) * 64 +
                                                     (((ks * 4 + quad) ^ l7) * 8)];
#pragma unroll
        for (int nf = 0; nf < 4; ++nf)
#pragma unroll
            for (int ks = 0; ks < 2; ++ks)
                bfr[nf][ks] = *(const s16x8*)&lsB[buf][(wn * 64 + nf * 16 + l15) * 64 +
                                                      (((ks * 4 + quad) ^ l7) * 8)];

        __builtin_amdgcn_s_setprio(1);
#pragma unroll
        for (int ks = 0; ks < 2; ++ks)
#pragma unroll
            for (int mf = 0; mf < 4; ++mf)
#pragma unroll
                for (int nf = 0; nf < 4; ++nf)
                    acc[mf][nf] = __builtin_amdgcn_mfma_f32_16x16x32_bf16(
                                      af[mf][ks], bfr[nf][ks], acc[mf][nf], 0, 0, 0);
        __builtin_amdgcn_s_setprio(0);
    }

    if (EPI == 0) {
#pragma unroll
        for (int mf = 0; mf < 4; ++mf) {
            int row = m0 + wm * 64 + mf * 16 + quad * 4;
#pragma unroll
            for (int nf = 0; nf < 4; ++nf) {
                int col = n0 + wn * 64 + nf * 16 + l15;
                float bv = bias[col];
#pragma unroll
                for (int r = 0; r < 4; ++r)
                    Cf[(size_t)(row + r) * N + col] = acc[mf][nf][r] + bv;
            }
        }
    } else {
#pragma unroll
        for (int mf = 0; mf < 4; ++mf) {
            int row = m0 + wm * 64 + mf * 16 + quad * 4;
#pragma unroll
            for (int nf = 0; nf < 4; ++nf) {
                int col = n0 + wn * 64 + nf * 16 + l15;
                float bv = bias[col];
                int sel = col >> 10, h = (col >> 6) & 15, hd = col & 63;
#pragma unroll
                for (int r = 0; r < 4; ++r) {
                    int rr = row + r;
                    int b = rr >> 11, s = rr & 2047;
                    short val = f2bf(acc[mf][nf][r] + bv);
                    if (sel == 0)      Qo[(((size_t)b * HH + h) * SS + s) * HDD + hd] = val;
                    else if (sel == 1) Ko[(((size_t)b * HH + h) * SS + s) * HDD + hd] = val;
                    else               Vo[(((size_t)b * HH + h) * HDD + hd) * SS + s] = val;
                }
            }
        }
    }
}

// ---------------- causal flash attention (32 rows/wave, GLL prefetch) ----------------
// (unchanged from round 6: 112 µs, 0 bank conflicts)
__global__ __launch_bounds__(256, 2)
void attn_kernel(const short* __restrict__ Q, const short* __restrict__ Kb,
                 const short* __restrict__ Vb, const int* __restrict__ mask,
                 short* __restrict__ O)
{
    __shared__ short lsK[2][64 * 64];      // [buf][key][hd] linear (GLL), src-swizzled
    __shared__ short lsV[2][64 * 64];      // [buf][hd][key] linear (GLL), src-swizzled
    __shared__ short lsP[4][32 * 64];      // per-wave P [qrow 32][key 64], granule-XOR
    __shared__ short lsM[SS];              // mask additive, bf16 (0 or -1e30)

    const int tid  = threadIdx.x;
    const int w    = tid >> 6, lane = tid & 63;
    const int quad = lane >> 4, l15 = lane & 15;
    const int bx = blockIdx.x, bh = blockIdx.y;
    const int b = bh >> 4;
    const size_t baseQK = (size_t)bh * SS * HDD;
    const size_t baseV  = (size_t)bh * HDD * SS;
    const float SC = 0.18033688f;          // (1/8) * log2(e)
    const int grow = lane >> 3;            // GLL: row-within-8 covered by this lane
    const int gcol = ((lane & 7) ^ grow) * 8;  // GLL: inverse-swizzled source col (shorts)
    const int l7 = l15 & 7;

    // stage mask -> lsM once (visible after first lds_barrier)
    {
        const int4* mp = (const int4*)(mask + b * SS);
        int4 a = mp[tid * 2], c = mp[tid * 2 + 1];
        const short NEG = f2bf(-1e30f);
        s16x8 mo;
        mo[0] = a.x ? (short)0 : NEG; mo[1] = a.y ? (short)0 : NEG;
        mo[2] = a.z ? (short)0 : NEG; mo[3] = a.w ? (short)0 : NEG;
        mo[4] = c.x ? (short)0 : NEG; mo[5] = c.y ? (short)0 : NEG;
        mo[6] = c.z ? (short)0 : NEG; mo[7] = c.w ? (short)0 : NEG;
        *(s16x8*)&lsM[tid * 8] = mo;
    }

    // issue tile (kv0) K/V global->LDS DMA into buffer buf: 4 GLL per wave
    auto issue = [&](int kv0, int buf) {
#pragma unroll
        for (int jj = 0; jj < 2; ++jj) {
            int row = w * 16 + jj * 8 + grow;                  // key row
            GLL(Kb + baseQK + (size_t)(kv0 + row) * HDD + gcol,
                &lsK[buf][(w * 2 + jj) * 512]);
        }
#pragma unroll
        for (int jj = 0; jj < 2; ++jj) {
            int row = w * 16 + jj * 8 + grow;                  // hd row
            GLL(Vb + baseV + (size_t)row * SS + kv0 + gcol,
                &lsV[buf][(w * 2 + jj) * 512]);
        }
    };

    for (int t = 0; t < 2; ++t) {
        const int qb = t ? bx : (15 - bx);  // heavy q-tile first
        const int q0 = qb * 128;
        const int qw0 = q0 + w * 32;        // this wave's first q-row

        s16x8 aq[2][2];
#pragma unroll
        for (int s = 0; s < 2; ++s)
#pragma unroll
            for (int ks = 0; ks < 2; ++ks)
                aq[s][ks] = *(const s16x8*)(Q + baseQK +
                    (size_t)(qw0 + s * 16 + l15) * HDD + ks * 32 + quad * 8);

        float m_r[2][4], l_r[2][4];
        f32x4 o_acc[2][4] = {};
#pragma unroll
        for (int s = 0; s < 2; ++s)
#pragma unroll
            for (int r = 0; r < 4; ++r) { m_r[s][r] = -1e30f; l_r[s][r] = 0.f; }

        const int ntiles = 2 * qb + 2;      // 64-key tiles; last two are diagonal

        lds_barrier();                      // prev t's reads done / mask visible
        issue(0, 0);

        auto tile = [&](auto CC, int kv0, int buf, int kvn) {
            constexpr bool CAUS = decltype(CC)::value;

            lds_barrier();                  // A: all waves done reading buf^1
            if (kvn >= 0) issue(kvn, buf ^ 1);

            float madd[4];
#pragma unroll
            for (int nt = 0; nt < 4; ++nt)
                madd[nt] = bf2f(lsM[kv0 + nt * 16 + l15]);

            if (kvn >= 0) asm volatile("s_waitcnt vmcnt(4)" ::: "memory");
            else          asm volatile("s_waitcnt vmcnt(0)" ::: "memory");
            __builtin_amdgcn_sched_barrier(0);
            __builtin_amdgcn_s_barrier();   // B: all waves' GLLs for buf landed
            __builtin_amdgcn_sched_barrier(0);

            // S = Q K^T (K fragment read once, reused for both row-sets)
            f32x4 sv[2][4];
#pragma unroll
            for (int s = 0; s < 2; ++s)
#pragma unroll
                for (int nt = 0; nt < 4; ++nt) sv[s][nt] = f32x4{};
#pragma unroll
            for (int ks = 0; ks < 2; ++ks)
#pragma unroll
                for (int nt = 0; nt < 4; ++nt) {
                    s16x8 kf = *(const s16x8*)&lsK[buf][(nt * 16 + l15) * 64 +
                                                       (((ks * 4 + quad) ^ l7) * 8)];
#pragma unroll
                    for (int s = 0; s < 2; ++s)
                        sv[s][nt] = __builtin_amdgcn_mfma_f32_16x16x32_bf16(
                                        aq[s][ks], kf, sv[s][nt], 0, 0, 0);
                }

#pragma unroll
            for (int s = 0; s < 2; ++s) {
                const int rowg0 = qw0 + s * 16 + quad * 4;
#pragma unroll
                for (int nt = 0; nt < 4; ++nt) {
                    int colg = kv0 + nt * 16 + l15;
#pragma unroll
                    for (int r = 0; r < 4; ++r) {
                        float scv = sv[s][nt][r] * SC + madd[nt];
                        if (CAUS && colg > rowg0 + r) scv = -1e30f;
                        sv[s][nt][r] = scv;
                    }
                }
            }

            // row max (16-lane groups), then T13 defer-max decision
            float rm[2][4];
#pragma unroll
            for (int s = 0; s < 2; ++s)
#pragma unroll
                for (int r = 0; r < 4; ++r) {
                    float v = fmaxf(fmaxf(sv[s][0][r], sv[s][1][r]),
                                    fmaxf(sv[s][2][r], sv[s][3][r]));
                    v = fmaxf(v, __shfl_xor(v, 1));
                    v = fmaxf(v, __shfl_xor(v, 2));
                    v = fmaxf(v, __shfl_xor(v, 4));
                    v = fmaxf(v, __shfl_xor(v, 8));
                    rm[s][r] = v;
                }
            float need = rm[0][0] - m_r[0][0];
#pragma unroll
            for (int s = 0; s < 2; ++s)
#pragma unroll
                for (int r = 0; r < 4; ++r)
                    need = fmaxf(need, rm[s][r] - m_r[s][r]);
            if (!__all(need <= 8.0f)) {     // rescale only when some row's max grew >8
#pragma unroll
                for (int s = 0; s < 2; ++s)
#pragma unroll
                    for (int r = 0; r < 4; ++r) {
                        float nm = fmaxf(m_r[s][r], rm[s][r]);
                        float al = __builtin_amdgcn_exp2f(m_r[s][r] - nm);
                        m_r[s][r] = nm;
                        l_r[s][r] *= al;
#pragma unroll
                        for (int ht = 0; ht < 4; ++ht)
                            o_acc[s][ht][r] *= al;
                    }
            }
            // P = exp2(S - m); per-lane partial l (sum-reduce deferred to epilogue)
#pragma unroll
            for (int s = 0; s < 2; ++s)
#pragma unroll
                for (int r = 0; r < 4; ++r) {
                    float rs = 0.f;
#pragma unroll
                    for (int nt = 0; nt < 4; ++nt) {
                        float p = __builtin_amdgcn_exp2f(sv[s][nt][r] - m_r[s][r]);
                        sv[s][nt][r] = p;
                        rs += p;
                    }
                    l_r[s][r] += rs;
                }

            // P -> wave-private buffer (granule-XOR swizzle; no barrier needed)
            short* lsPw = lsP[w];
#pragma unroll
            for (int s = 0; s < 2; ++s)
#pragma unroll
                for (int nt = 0; nt < 4; ++nt)
#pragma unroll
                    for (int r = 0; r < 4; ++r) {
                        int prow = s * 16 + quad * 4 + r;
                        lsPw[prow * 64 + (((nt * 2 + (l15 >> 3)) ^ (prow & 7)) << 3) + l7]
                            = f2bf(sv[s][nt][r]);
                    }
            asm volatile("s_waitcnt lgkmcnt(0)" ::: "memory");
            __builtin_amdgcn_sched_barrier(0);

            // O += P V (V fragment read once, reused for both row-sets)
            s16x8 ap[2][2];
#pragma unroll
            for (int s = 0; s < 2; ++s)
#pragma unroll
                for (int k2 = 0; k2 < 2; ++k2)
                    ap[s][k2] = *(const s16x8*)&lsPw[(s * 16 + l15) * 64 +
                                                     (((k2 * 4 + quad) ^ l7) << 3)];
#pragma unroll
            for (int ht = 0; ht < 4; ++ht)
#pragma unroll
                for (int k2 = 0; k2 < 2; ++k2) {
                    s16x8 vf = *(const s16x8*)&lsV[buf][(ht * 16 + l15) * 64 +
                                                        (((k2 * 4 + quad) ^ l7) * 8)];
#pragma unroll
                    for (int s = 0; s < 2; ++s)
                        o_acc[s][ht] = __builtin_amdgcn_mfma_f32_16x16x32_bf16(
                                           ap[s][k2], vf, o_acc[s][ht], 0, 0, 0);
                }
        };

        for (int kt = 0; kt < ntiles; ++kt) {
            const int kvn = (kt + 1 < ntiles) ? (kt + 1) * 64 : -1;
            if (kt >= 2 * qb) tile(std::true_type{},  kt * 64, kt & 1, kvn);
            else              tile(std::false_type{}, kt * 64, kt & 1, kvn);
        }

        // epilogue: reduce l over 16-lane groups, then O/l -> (b, s, h*64+hd) bf16
        const int hcol = (bh & 15) * HDD;
#pragma unroll
        for (int s = 0; s < 2; ++s)
#pragma unroll
            for (int r = 0; r < 4; ++r) {
                float ls = l_r[s][r];
                ls += __shfl_xor(ls, 1);
                ls += __shfl_xor(ls, 2);
                ls += __shfl_xor(ls, 4);
                ls += __shfl_xor(ls, 8);
                float inv = 1.0f / ls;
                int srow = qw0 + s * 16 + quad * 4 + r;
                size_t base = ((size_t)b * SS + srow) * DD + hcol;
#pragma unroll
                for (int ht = 0; ht < 4; ++ht)
                    O[base + ht * 16 + l15] = f2bf(o_acc[s][ht][r] * inv);
            }
    }
}

// ---------------- launch ----------------
extern "C" void kernel_launch(void* const* d_in, const int* in_sizes, int n_in,
                              void* d_out, int out_size, void* d_ws, size_t ws_size,
                              hipStream_t stream) {
    const float* x     = (const float*)d_in[0];
    const int*   mask  = (const int*)d_in[1];
    const float* qkv_w = (const float*)d_in[2];
    const float* qkv_b = (const float*)d_in[3];
    const float* out_w = (const float*)d_in[4];
    const float* out_b = (const float*)d_in[5];
    float* out = (float*)d_out;

    const size_t M1 = (size_t)BB * SS;       // 8192
    short* ws  = (short*)d_ws;
    short* xb  = ws;
    short* qwb = xb  + M1 * DD;
    short* owb = qwb + (size_t)3 * DD * DD;
    short* Qb  = owb + (size_t)DD * DD;
    short* Kb  = Qb  + M1 * DD;
    short* Vb  = Kb  + M1 * DD;
    short* Ob  = Vb  + M1 * DD;

    cvt_kernel<<<(int)(M1 * DD / 8 / 256), 256, 0, stream>>>(x, xb, (int)(M1 * DD));
    cvt_kernel<<<3 * DD * DD / 8 / 256, 256, 0, stream>>>(qkv_w, qwb, 3 * DD * DD);
    cvt_kernel<<<DD * DD / 8 / 256, 256, 0, stream>>>(out_w, owb, DD * DD);

    // qkv: M=8192, N=3072 -> 64 x 12 = 768 blocks (3 exact CU rounds)
    gemm256<1><<<768, 512, 0, stream>>>(xb, qwb, qkv_b, nullptr,
                                        Qb, Kb, Vb, 8192, 3072, 1024, 12);
    attn_kernel<<<dim3(8, BB * HH), 256, 0, stream>>>(Qb, Kb, Vb, mask, Ob);
    // out: M=8192, N=1024 -> 64 x 4 = 256 blocks (1 exact CU round)
    gemm256<0><<<256, 512, 0, stream>>>(Ob, owb, out_b, out,
                                        nullptr, nullptr, nullptr, 8192, 1024, 1024, 4);
}

// Round 8
// 308.404 us; speedup vs baseline: 1.0755x; 1.0755x over previous
//
#include <hip/hip_runtime.h>
#include <stdint.h>
#include <type_traits>

// Problem constants
#define BB  4
#define SS  2048
#define DD  1024
#define HH  16
#define HDD 64

typedef __attribute__((ext_vector_type(8))) short s16x8;   // 8 bf16 (4 VGPRs)
typedef __attribute__((ext_vector_type(4))) float f32x4;   // MFMA C/D

__device__ inline short f2bf(float f) {
    union { float f; unsigned int u; } v; v.f = f;
    unsigned int r = (v.u + 0x7fffu + ((v.u >> 16) & 1u)) >> 16; // RNE
    return (short)r;
}

__device__ inline float bf2f(short s) {
    union { unsigned int u; float f; } v;
    v.u = ((unsigned int)(unsigned short)s) << 16;
    return v.f;
}

#define GLL(gp, lp) __builtin_amdgcn_global_load_lds( \
    (const __attribute__((address_space(1))) void*)(gp), \
    (__attribute__((address_space(3))) void*)(lp), 16, 0, 0)

// Raw barrier: orders this wave's LDS ops (lgkmcnt) then syncs. Does NOT
// drain vmcnt -> global_load_lds prefetch stays in flight across it.
__device__ inline void lds_barrier() {
    asm volatile("s_waitcnt lgkmcnt(0)" ::: "memory");
    __builtin_amdgcn_sched_barrier(0);
    __builtin_amdgcn_s_barrier();
    __builtin_amdgcn_sched_barrier(0);
}

// ---------------- fp32 -> bf16 cast (n % 8 == 0) ----------------
__global__ void cvt_kernel(const float* __restrict__ src, short* __restrict__ dst, int n) {
    int i = (blockIdx.x * 256 + threadIdx.x) * 8;
    if (i >= n) return;
    const float4* s = (const float4*)(src + i);
    float4 a = s[0], b = s[1];
    s16x8 o;
    o[0]=f2bf(a.x); o[1]=f2bf(a.y); o[2]=f2bf(a.z); o[3]=f2bf(a.w);
    o[4]=f2bf(b.x); o[5]=f2bf(b.y); o[6]=f2bf(b.z); o[7]=f2bf(b.w);
    *(s16x8*)(dst + i) = o;
}

// ---------------- GEMM C = A @ B^T + bias (BM=128 BN=128 BK=64, GLL dbuf) ----------
// Round-7 post-mortem: the 128x256 96KB-LDS version ran at 1 block/CU; with a
// lockstep 2-barrier K-loop there was no co-resident block to overlap the
// vmcnt+barrier stall (MfmaUtil 18%, occupancy 17.7%). This version keeps the
// proven elements (0-conflict both-sides granule-XOR swizzle, counted vmcnt never
// drained in-loop, raw barriers, setprio, XCD swizzle) but shrinks to 128x128/
// 64 KB LDS -> 2 INDEPENDENT blocks/CU whose stalls overlap (m97-style implicit
// pipelining). 256 threads = 4 waves (2Mx2N), per-wave 64x64 (acc[4][4]).
// Per K-tile per wave: 8 GLL (A 4 + B 4) -> steady-state vmcnt(8).
// Grids: qkv 64x24=1536 = 2/CU x 3 exact rounds; out 64x8=512 = 2/CU x 1 round.
template<int EPI>
__global__ __launch_bounds__(256, 2)
void gemm128(const short* __restrict__ A, const short* __restrict__ Bw,
             const float* __restrict__ bias, float* __restrict__ Cf,
             short* __restrict__ Qo, short* __restrict__ Ko, short* __restrict__ Vo,
             int M, int N, int K, int nbx)
{
    __shared__ short lsA[2][128 * 64];
    __shared__ short lsB[2][128 * 64];

    const int tid  = threadIdx.x;
    const int w    = tid >> 6, lane = tid & 63;
    const int quad = lane >> 4, l15 = lane & 15;
    const int wm = w >> 1, wn = w & 1;
    // T1 XCD-aware swizzle (gridDim.x % 8 == 0 guaranteed by launch)
    const int cpx = gridDim.x >> 3;
    const int swz = (blockIdx.x & 7) * cpx + (blockIdx.x >> 3);
    const int m0 = (swz / nbx) * 128, n0 = (swz % nbx) * 128;
    const int grow = lane >> 3;                 // row-within-octet this lane covers
    const int gcol = ((lane & 7) ^ grow) * 8;   // inverse-swizzled source col (shorts)
    const int l7 = l15 & 7;

    f32x4 acc[4][4] = {};

    auto issue = [&](int kt, int buf) {
#pragma unroll
        for (int jj = 0; jj < 4; ++jj) {        // A: 128 rows = 16 octets, 4/wave
            int row = w * 32 + jj * 8 + grow;
            GLL(A + (size_t)(m0 + row) * K + kt * 64 + gcol,
                &lsA[buf][(w * 4 + jj) * 512]);
        }
#pragma unroll
        for (int jj = 0; jj < 4; ++jj) {        // B: 128 rows = 16 octets, 4/wave
            int row = w * 32 + jj * 8 + grow;
            GLL(Bw + (size_t)(n0 + row) * K + kt * 64 + gcol,
                &lsB[buf][(w * 4 + jj) * 512]);
        }
    };

    const int NT = K >> 6;                      // BK=64 K-tiles
    issue(0, 0);
    for (int t = 0; t < NT; ++t) {
        const int buf = t & 1;
        lds_barrier();                          // A: all waves done reading buf^1
        if (t + 1 < NT) {
            issue(t + 1, buf ^ 1);
            asm volatile("s_waitcnt vmcnt(8)" ::: "memory");
        } else {
            asm volatile("s_waitcnt vmcnt(0)" ::: "memory");
        }
        __builtin_amdgcn_sched_barrier(0);
        __builtin_amdgcn_s_barrier();           // B: tile t fully staged (all waves)
        __builtin_amdgcn_sched_barrier(0);

        s16x8 af[4][2], bfr[4][2];
#pragma unroll
        for (int mf = 0; mf < 4; ++mf)
#pragma unroll
            for (int ks = 0; ks < 2; ++ks)
                af[mf][ks] = *(const s16x8*)&lsA[buf][(wm * 64 + mf * 16 + l15) * 64 +
                                                     (((ks * 4 + quad) ^ l7) * 8)];
#pragma unroll
        for (int nf = 0; nf < 4; ++nf)
#pragma unroll
            for (int ks = 0; ks < 2; ++ks)
                bfr[nf][ks] = *(const s16x8*)&lsB[buf][(wn * 64 + nf * 16 + l15) * 64 +
                                                      (((ks * 4 + quad) ^ l7) * 8)];

        __builtin_amdgcn_s_setprio(1);
#pragma unroll
        for (int ks = 0; ks < 2; ++ks)
#pragma unroll
            for (int mf = 0; mf < 4; ++mf)
#pragma unroll
                for (int nf = 0; nf < 4; ++nf)
                    acc[mf][nf] = __builtin_amdgcn_mfma_f32_16x16x32_bf16(
                                      af[mf][ks], bfr[nf][ks], acc[mf][nf], 0, 0, 0);
        __builtin_amdgcn_s_setprio(0);
    }

    if (EPI == 0) {
#pragma unroll
        for (int mf = 0; mf < 4; ++mf) {
            int row = m0 + wm * 64 + mf * 16 + quad * 4;
#pragma unroll
            for (int nf = 0; nf < 4; ++nf) {
                int col = n0 + wn * 64 + nf * 16 + l15;
                float bv = bias[col];
#pragma unroll
                for (int r = 0; r < 4; ++r)
                    Cf[(size_t)(row + r) * N + col] = acc[mf][nf][r] + bv;
            }
        }
    } else {
#pragma unroll
        for (int mf = 0; mf < 4; ++mf) {
            int row = m0 + wm * 64 + mf * 16 + quad * 4;
#pragma unroll
            for (int nf = 0; nf < 4; ++nf) {
                int col = n0 + wn * 64 + nf * 16 + l15;
                float bv = bias[col];
                int sel = col >> 10, h = (col >> 6) & 15, hd = col & 63;
#pragma unroll
                for (int r = 0; r < 4; ++r) {
                    int rr = row + r;
                    int b = rr >> 11, s = rr & 2047;
                    short val = f2bf(acc[mf][nf][r] + bv);
                    if (sel == 0)      Qo[(((size_t)b * HH + h) * SS + s) * HDD + hd] = val;
                    else if (sel == 1) Ko[(((size_t)b * HH + h) * SS + s) * HDD + hd] = val;
                    else               Vo[(((size_t)b * HH + h) * HDD + hd) * SS + s] = val;
                }
            }
        }
    }
}

// ---------------- causal flash attention (32 rows/wave, GLL prefetch) ----------------
// (unchanged from round 6: 112 µs, 0 bank conflicts)
__global__ __launch_bounds__(256, 2)
void attn_kernel(const short* __restrict__ Q, const short* __restrict__ Kb,
                 const short* __restrict__ Vb, const int* __restrict__ mask,
                 short* __restrict__ O)
{
    __shared__ short lsK[2][64 * 64];      // [buf][key][hd] linear (GLL), src-swizzled
    __shared__ short lsV[2][64 * 64];      // [buf][hd][key] linear (GLL), src-swizzled
    __shared__ short lsP[4][32 * 64];      // per-wave P [qrow 32][key 64], granule-XOR
    __shared__ short lsM[SS];              // mask additive, bf16 (0 or -1e30)

    const int tid  = threadIdx.x;
    const int w    = tid >> 6, lane = tid & 63;
    const int quad = lane >> 4, l15 = lane & 15;
    const int bx = blockIdx.x, bh = blockIdx.y;
    const int b = bh >> 4;
    const size_t baseQK = (size_t)bh * SS * HDD;
    const size_t baseV  = (size_t)bh * HDD * SS;
    const float SC = 0.18033688f;          // (1/8) * log2(e)
    const int grow = lane >> 3;            // GLL: row-within-8 covered by this lane
    const int gcol = ((lane & 7) ^ grow) * 8;  // GLL: inverse-swizzled source col (shorts)
    const int l7 = l15 & 7;

    // stage mask -> lsM once (visible after first lds_barrier)
    {
        const int4* mp = (const int4*)(mask + b * SS);
        int4 a = mp[tid * 2], c = mp[tid * 2 + 1];
        const short NEG = f2bf(-1e30f);
        s16x8 mo;
        mo[0] = a.x ? (short)0 : NEG; mo[1] = a.y ? (short)0 : NEG;
        mo[2] = a.z ? (short)0 : NEG; mo[3] = a.w ? (short)0 : NEG;
        mo[4] = c.x ? (short)0 : NEG; mo[5] = c.y ? (short)0 : NEG;
        mo[6] = c.z ? (short)0 : NEG; mo[7] = c.w ? (short)0 : NEG;
        *(s16x8*)&lsM[tid * 8] = mo;
    }

    // issue tile (kv0) K/V global->LDS DMA into buffer buf: 4 GLL per wave
    auto issue = [&](int kv0, int buf) {
#pragma unroll
        for (int jj = 0; jj < 2; ++jj) {
            int row = w * 16 + jj * 8 + grow;                  // key row
            GLL(Kb + baseQK + (size_t)(kv0 + row) * HDD + gcol,
                &lsK[buf][(w * 2 + jj) * 512]);
        }
#pragma unroll
        for (int jj = 0; jj < 2; ++jj) {
            int row = w * 16 + jj * 8 + grow;                  // hd row
            GLL(Vb + baseV + (size_t)row * SS + kv0 + gcol,
                &lsV[buf][(w * 2 + jj) * 512]);
        }
    };

    for (int t = 0; t < 2; ++t) {
        const int qb = t ? bx : (15 - bx);  // heavy q-tile first
        const int q0 = qb * 128;
        const int qw0 = q0 + w * 32;        // this wave's first q-row

        s16x8 aq[2][2];
#pragma unroll
        for (int s = 0; s < 2; ++s)
#pragma unroll
            for (int ks = 0; ks < 2; ++ks)
                aq[s][ks] = *(const s16x8*)(Q + baseQK +
                    (size_t)(qw0 + s * 16 + l15) * HDD + ks * 32 + quad * 8);

        float m_r[2][4], l_r[2][4];
        f32x4 o_acc[2][4] = {};
#pragma unroll
        for (int s = 0; s < 2; ++s)
#pragma unroll
            for (int r = 0; r < 4; ++r) { m_r[s][r] = -1e30f; l_r[s][r] = 0.f; }

        const int ntiles = 2 * qb + 2;      // 64-key tiles; last two are diagonal

        lds_barrier();                      // prev t's reads done / mask visible
        issue(0, 0);

        auto tile = [&](auto CC, int kv0, int buf, int kvn) {
            constexpr bool CAUS = decltype(CC)::value;

            lds_barrier();                  // A: all waves done reading buf^1
            if (kvn >= 0) issue(kvn, buf ^ 1);

            float madd[4];
#pragma unroll
            for (int nt = 0; nt < 4; ++nt)
                madd[nt] = bf2f(lsM[kv0 + nt * 16 + l15]);

            if (kvn >= 0) asm volatile("s_waitcnt vmcnt(4)" ::: "memory");
            else          asm volatile("s_waitcnt vmcnt(0)" ::: "memory");
            __builtin_amdgcn_sched_barrier(0);
            __builtin_amdgcn_s_barrier();   // B: all waves' GLLs for buf landed
            __builtin_amdgcn_sched_barrier(0);

            // S = Q K^T (K fragment read once, reused for both row-sets)
            f32x4 sv[2][4];
#pragma unroll
            for (int s = 0; s < 2; ++s)
#pragma unroll
                for (int nt = 0; nt < 4; ++nt) sv[s][nt] = f32x4{};
#pragma unroll
            for (int ks = 0; ks < 2; ++ks)
#pragma unroll
                for (int nt = 0; nt < 4; ++nt) {
                    s16x8 kf = *(const s16x8*)&lsK[buf][(nt * 16 + l15) * 64 +
                                                       (((ks * 4 + quad) ^ l7) * 8)];
#pragma unroll
                    for (int s = 0; s < 2; ++s)
                        sv[s][nt] = __builtin_amdgcn_mfma_f32_16x16x32_bf16(
                                        aq[s][ks], kf, sv[s][nt], 0, 0, 0);
                }

#pragma unroll
            for (int s = 0; s < 2; ++s) {
                const int rowg0 = qw0 + s * 16 + quad * 4;
#pragma unroll
                for (int nt = 0; nt < 4; ++nt) {
                    int colg = kv0 + nt * 16 + l15;
#pragma unroll
                    for (int r = 0; r < 4; ++r) {
                        float scv = sv[s][nt][r] * SC + madd[nt];
                        if (CAUS && colg > rowg0 + r) scv = -1e30f;
                        sv[s][nt][r] = scv;
                    }
                }
            }

            // row max (16-lane groups), then T13 defer-max decision
            float rm[2][4];
#pragma unroll
            for (int s = 0; s < 2; ++s)
#pragma unroll
                for (int r = 0; r < 4; ++r) {
                    float v = fmaxf(fmaxf(sv[s][0][r], sv[s][1][r]),
                                    fmaxf(sv[s][2][r], sv[s][3][r]));
                    v = fmaxf(v, __shfl_xor(v, 1));
                    v = fmaxf(v, __shfl_xor(v, 2));
                    v = fmaxf(v, __shfl_xor(v, 4));
                    v = fmaxf(v, __shfl_xor(v, 8));
                    rm[s][r] = v;
                }
            float need = rm[0][0] - m_r[0][0];
#pragma unroll
            for (int s = 0; s < 2; ++s)
#pragma unroll
                for (int r = 0; r < 4; ++r)
                    need = fmaxf(need, rm[s][r] - m_r[s][r]);
            if (!__all(need <= 8.0f)) {     // rescale only when some row's max grew >8
#pragma unroll
                for (int s = 0; s < 2; ++s)
#pragma unroll
                    for (int r = 0; r < 4; ++r) {
                        float nm = fmaxf(m_r[s][r], rm[s][r]);
                        float al = __builtin_amdgcn_exp2f(m_r[s][r] - nm);
                        m_r[s][r] = nm;
                        l_r[s][r] *= al;
#pragma unroll
                        for (int ht = 0; ht < 4; ++ht)
                            o_acc[s][ht][r] *= al;
                    }
            }
            // P = exp2(S - m); per-lane partial l (sum-reduce deferred to epilogue)
#pragma unroll
            for (int s = 0; s < 2; ++s)
#pragma unroll
                for (int r = 0; r < 4; ++r) {
                    float rs = 0.f;
#pragma unroll
                    for (int nt = 0; nt < 4; ++nt) {
                        float p = __builtin_amdgcn_exp2f(sv[s][nt][r] - m_r[s][r]);
                        sv[s][nt][r] = p;
                        rs += p;
                    }
                    l_r[s][r] += rs;
                }

            // P -> wave-private buffer (granule-XOR swizzle; no barrier needed)
            short* lsPw = lsP[w];
#pragma unroll
            for (int s = 0; s < 2; ++s)
#pragma unroll
                for (int nt = 0; nt < 4; ++nt)
#pragma unroll
                    for (int r = 0; r < 4; ++r) {
                        int prow = s * 16 + quad * 4 + r;
                        lsPw[prow * 64 + (((nt * 2 + (l15 >> 3)) ^ (prow & 7)) << 3) + l7]
                            = f2bf(sv[s][nt][r]);
                    }
            asm volatile("s_waitcnt lgkmcnt(0)" ::: "memory");
            __builtin_amdgcn_sched_barrier(0);

            // O += P V (V fragment read once, reused for both row-sets)
            s16x8 ap[2][2];
#pragma unroll
            for (int s = 0; s < 2; ++s)
#pragma unroll
                for (int k2 = 0; k2 < 2; ++k2)
                    ap[s][k2] = *(const s16x8*)&lsPw[(s * 16 + l15) * 64 +
                                                     (((k2 * 4 + quad) ^ l7) << 3)];
#pragma unroll
            for (int ht = 0; ht < 4; ++ht)
#pragma unroll
                for (int k2 = 0; k2 < 2; ++k2) {
                    s16x8 vf = *(const s16x8*)&lsV[buf][(ht * 16 + l15) * 64 +
                                                        (((k2 * 4 + quad) ^ l7) * 8)];
#pragma unroll
                    for (int s = 0; s < 2; ++s)
                        o_acc[s][ht] = __builtin_amdgcn_mfma_f32_16x16x32_bf16(
                                           ap[s][k2], vf, o_acc[s][ht], 0, 0, 0);
                }
        };

        for (int kt = 0; kt < ntiles; ++kt) {
            const int kvn = (kt + 1 < ntiles) ? (kt + 1) * 64 : -1;
            if (kt >= 2 * qb) tile(std::true_type{},  kt * 64, kt & 1, kvn);
            else              tile(std::false_type{}, kt * 64, kt & 1, kvn);
        }

        // epilogue: reduce l over 16-lane groups, then O/l -> (b, s, h*64+hd) bf16
        const int hcol = (bh & 15) * HDD;
#pragma unroll
        for (int s = 0; s < 2; ++s)
#pragma unroll
            for (int r = 0; r < 4; ++r) {
                float ls = l_r[s][r];
                ls += __shfl_xor(ls, 1);
                ls += __shfl_xor(ls, 2);
                ls += __shfl_xor(ls, 4);
                ls += __shfl_xor(ls, 8);
                float inv = 1.0f / ls;
                int srow = qw0 + s * 16 + quad * 4 + r;
                size_t base = ((size_t)b * SS + srow) * DD + hcol;
#pragma unroll
                for (int ht = 0; ht < 4; ++ht)
                    O[base + ht * 16 + l15] = f2bf(o_acc[s][ht][r] * inv);
            }
    }
}

// ---------------- launch ----------------
extern "C" void kernel_launch(void* const* d_in, const int* in_sizes, int n_in,
                              void* d_out, int out_size, void* d_ws, size_t ws_size,
                              hipStream_t stream) {
    const float* x     = (const float*)d_in[0];
    const int*   mask  = (const int*)d_in[1];
    const float* qkv_w = (const float*)d_in[2];
    const float* qkv_b = (const float*)d_in[3];
    const float* out_w = (const float*)d_in[4];
    const float* out_b = (const float*)d_in[5];
    float* out = (float*)d_out;

    const size_t M1 = (size_t)BB * SS;       // 8192
    short* ws  = (short*)d_ws;
    short* xb  = ws;
    short* qwb = xb  + M1 * DD;
    short* owb = qwb + (size_t)3 * DD * DD;
    short* Qb  = owb + (size_t)DD * DD;
    short* Kb  = Qb  + M1 * DD;
    short* Vb  = Kb  + M1 * DD;
    short* Ob  = Vb  + M1 * DD;

    cvt_kernel<<<(int)(M1 * DD / 8 / 256), 256, 0, stream>>>(x, xb, (int)(M1 * DD));
    cvt_kernel<<<3 * DD * DD / 8 / 256, 256, 0, stream>>>(qkv_w, qwb, 3 * DD * DD);
    cvt_kernel<<<DD * DD / 8 / 256, 256, 0, stream>>>(out_w, owb, DD * DD);

    // qkv: M=8192, N=3072 -> 64 x 24 = 1536 blocks (2/CU x 3 exact rounds)
    gemm128<1><<<1536, 256, 0, stream>>>(xb, qwb, qkv_b, nullptr,
                                         Qb, Kb, Vb, 8192, 3072, 1024, 24);
    attn_kernel<<<dim3(8, BB * HH), 256, 0, stream>>>(Qb, Kb, Vb, mask, Ob);
    // out: M=8192, N=1024 -> 64 x 8 = 512 blocks (2/CU x 1 round)
    gemm128<0><<<512, 256, 0, stream>>>(Ob, owb, out_b, out,
                                        nullptr, nullptr, nullptr, 8192, 1024, 1024, 8);
}